// Round 1
// baseline (599.428 us; speedup 1.0000x reference)
//
#include <hip/hip_runtime.h>
#include <hip/hip_bf16.h>

typedef __bf16 bf16;
typedef __bf16 bf16x8 __attribute__((ext_vector_type(8)));
typedef float f32x4 __attribute__((ext_vector_type(4)));

#define ROWS 64
#define LDST 264  // 256 + 8 pad: row stride 528 B (16B-aligned)

// ---------------- prep: transpose all four [6][256][256] fp32 weight sets -> bf16 [N][K] ----------------
// N rows are stored PERMUTED within each 32-group: logical col c -> slot (c even ? c/2 : 16+c/2).
// This makes MFMA lane lx own logical cols (2lx, 2lx+1), so activation stores are shuffle-free
// u32 packs AND the stored activation ends up in standard logical layout (no downstream K-perm).
__global__ void transpose_all(const float* __restrict__ w0, const float* __restrict__ w1,
                              const float* __restrict__ w2, const float* __restrict__ w3,
                              bf16* __restrict__ out)
{
    __shared__ float tile[64][65];
    const int mz  = blockIdx.z;             // 0..23 = mat*6 + level
    const int mat = mz / 6;
    const float* srcs[4] = {w0, w1, w2, w3};
    const float* src = srcs[mat] + (size_t)(mz % 6) * 65536;
    bf16* dst = out + (size_t)mz * 65536;
    const int k0 = blockIdx.x * 64;
    const int n0 = blockIdx.y * 64;
    const int tx = threadIdx.x & 63, ty = threadIdx.x >> 6;
#pragma unroll
    for (int i = ty; i < 64; i += 4)
        tile[i][tx] = src[(size_t)(k0 + i) * 256 + n0 + tx];
    __syncthreads();
#pragma unroll
    for (int i = ty; i < 64; i += 4) {
        int n  = n0 + i;
        int o  = n & 31;
        int ns = (n & ~31) | ((o & 1) ? 16 + (o >> 1) : (o >> 1));
        dst[(size_t)ns * 256 + k0 + tx] = (bf16)tile[tx][i];
    }
}

// ---------------- prep: [6][256][10] -> [6][16][256] bf16, transposed + zero-padded (both w3s) ----------------
__global__ void prep_small(const float* __restrict__ cw3, const float* __restrict__ rw3,
                           bf16* __restrict__ outc, bf16* __restrict__ outr)
{
    int idx = blockIdx.x * 256 + threadIdx.x;  // 0..49151
    const float* w = (idx < 24576) ? cw3 : rw3;
    bf16* o = (idx < 24576) ? outc : outr;
    int j = (idx < 24576) ? idx : idx - 24576;
    int k = j & 255;
    int n = (j >> 8) & 15;
    int l = j >> 12;
    float v = (n < 10) ? w[((size_t)l * 256 + k) * 10 + n] : 0.0f;
    o[j] = (bf16)v;
}

// ---------------- helpers ----------------
__device__ __forceinline__ unsigned int pack2(float lo, float hi)
{
    union { bf16 h[2]; unsigned int u; } p;
    p.h[0] = (bf16)lo; p.h[1] = (bf16)hi;
    return p.u;
}

// VALU-pipe lane reduce step (replaces ds_swizzle shuffles): x += x[dpp-permuted lane]
template<int CTRL>
__device__ __forceinline__ float dppadd(float x)
{
    int y = __builtin_amdgcn_update_dpp(0, __float_as_int(x), CTRL, 0xF, 0xF, true);
    return x + __int_as_float(y);
}
// full sum over the 16-lane DPP row (== one quad's lx range)
__device__ __forceinline__ float dppsum16(float x)
{
    x = dppadd<0xB1>(x);   // quad_perm [1,0,3,2]  (xor 1)
    x = dppadd<0x4E>(x);   // quad_perm [2,3,0,1]  (xor 2)
    x = dppadd<0x141>(x);  // row_half_mirror      (pairs 4-groups)
    x = dppadd<0x140>(x);  // row_mirror           (pairs 8-groups)
    return x;
}

// 64x256 tile GEMM, 4 waves: wave owns 64 logical cols [w*64, w*64+64) via 4 n-tiles.
// Weight storage rows are the permuted slots, so addressing is linear.
__device__ __forceinline__ void gemm64w4(const bf16* __restrict__ bufIn,
                                         const bf16* __restrict__ wt,
                                         int w, int lane, f32x4 acc[4][4])
{
    const int quad = lane >> 4, lx = lane & 15;
    const int nrow0 = w * 64;
#pragma unroll
    for (int mt = 0; mt < 4; mt++)
#pragma unroll
        for (int nt = 0; nt < 4; nt++)
            acc[mt][nt] = f32x4{0.f, 0.f, 0.f, 0.f};
#pragma unroll
    for (int kk = 0; kk < 8; kk++) {
        const int k0 = kk * 32 + quad * 8;
        bf16x8 a[4], b[4];
#pragma unroll
        for (int mt = 0; mt < 4; mt++)
            a[mt] = *(const bf16x8*)&bufIn[(mt * 16 + lx) * LDST + k0];
#pragma unroll
        for (int nt = 0; nt < 4; nt++)
            b[nt] = *(const bf16x8*)&wt[(nrow0 + nt * 16 + lx) * 256 + k0];
#pragma unroll
        for (int mt = 0; mt < 4; mt++)
#pragma unroll
            for (int nt = 0; nt < 4; nt++)
                acc[mt][nt] = __builtin_amdgcn_mfma_f32_16x16x32_bf16(a[mt], b[nt], acc[mt][nt], 0, 0, 0);
    }
}

// 16x256 @ 256x16 GEMM (final small layers)
__device__ __forceinline__ f32x4 gemm16(const bf16* __restrict__ bufIn,
                                        const bf16* __restrict__ wt,
                                        int mrow0, int lane)
{
    const int quad = lane >> 4, lx = lane & 15;
    f32x4 acc = f32x4{0.f, 0.f, 0.f, 0.f};
#pragma unroll
    for (int kk = 0; kk < 8; kk++) {
        const int k0 = kk * 32 + quad * 8;
        bf16x8 a = *(const bf16x8*)&bufIn[(mrow0 + lx) * LDST + k0];
        bf16x8 b = *(const bf16x8*)&wt[lx * 256 + k0];
        acc = __builtin_amdgcn_mfma_f32_16x16x32_bf16(a, b, acc, 0, 0, 0);
    }
    return acc;
}

// logical col handled by (nt, lx) within a wave's 64-col slab
__device__ __forceinline__ int colof(int w, int nt, int lx)
{
    return w * 64 + ((nt >> 1) << 5) + 2 * lx + (nt & 1);
}

// add bias in place, compute per-row (sum, sumsq) via DPP, write to redC
__device__ __forceinline__ void ln_stats(f32x4 acc[4][4], const float* __restrict__ bias,
                                         float2 (*redC)[ROWS], int w, int lane)
{
    const int quad = lane >> 4, lx = lane & 15;
    float bv[4];
#pragma unroll
    for (int nt = 0; nt < 4; nt++) bv[nt] = bias[colof(w, nt, lx)];
#pragma unroll
    for (int mt = 0; mt < 4; mt++) {
        float s[4], ss[4];
#pragma unroll
        for (int r = 0; r < 4; r++) {
            float a0 = acc[mt][0][r] + bv[0];
            float a1 = acc[mt][1][r] + bv[1];
            float a2 = acc[mt][2][r] + bv[2];
            float a3 = acc[mt][3][r] + bv[3];
            acc[mt][0][r] = a0; acc[mt][1][r] = a1; acc[mt][2][r] = a2; acc[mt][3][r] = a3;
            s[r]  = (a0 + a1) + (a2 + a3);
            ss[r] = (a0 * a0 + a1 * a1) + (a2 * a2 + a3 * a3);
        }
#pragma unroll
        for (int r = 0; r < 4; r++) {
            s[r]  = dppsum16(s[r]);
            ss[r] = dppsum16(ss[r]);
        }
        if (lx == 0) {
#pragma unroll
            for (int r = 0; r < 4; r++)
                redC[w][mt * 16 + quad * 4 + r] = make_float2(s[r], ss[r]);
        }
    }
}

// cross-wave stat reduce (one wave, tid < ROWS)
__device__ __forceinline__ void stat_reduce(const float2 (*redC)[ROWS], float2* __restrict__ stat, int tid)
{
    float sx = 0.f, sy = 0.f;
#pragma unroll
    for (int w = 0; w < 4; w++) { float2 t = redC[w][tid]; sx += t.x; sy += t.y; }
    float mean = sx * (1.f / 256.f);
    float var  = sy * (1.f / 256.f) - mean * mean;
    stat[tid] = make_float2(mean, rsqrtf(var + 1e-5f));
}

// normalize + relu in place
__device__ __forceinline__ void ln_norm(f32x4 acc[4][4],
                                        const float* __restrict__ g, const float* __restrict__ b,
                                        const float2* __restrict__ stat, int w, int lane)
{
    const int quad = lane >> 4, lx = lane & 15;
    float gv[4], bv[4];
#pragma unroll
    for (int nt = 0; nt < 4; nt++) {
        int c = colof(w, nt, lx);
        gv[nt] = g[c]; bv[nt] = b[c];
    }
#pragma unroll
    for (int mt = 0; mt < 4; mt++)
#pragma unroll
        for (int r = 0; r < 4; r++) {
            float2 st = stat[mt * 16 + quad * 4 + r];
#pragma unroll
            for (int nt = 0; nt < 4; nt++)
                acc[mt][nt][r] = fmaxf((acc[mt][nt][r] - st.x) * st.y * gv[nt] + bv[nt], 0.f);
        }
}

__device__ __forceinline__ void bias_relu4(f32x4 acc[4][4], const float* __restrict__ bias,
                                           int w, int lane)
{
    const int lx = lane & 15;
    float bv[4];
#pragma unroll
    for (int nt = 0; nt < 4; nt++) bv[nt] = bias[colof(w, nt, lx)];
#pragma unroll
    for (int mt = 0; mt < 4; mt++)
#pragma unroll
        for (int nt = 0; nt < 4; nt++)
#pragma unroll
            for (int r = 0; r < 4; r++)
                acc[mt][nt][r] = fmaxf(acc[mt][nt][r] + bv[nt], 0.f);
}

// shuffle-free store: lane lx owns logical cols (2lx, 2lx+1) of each 32-slab -> two u32 packs
__device__ __forceinline__ void store_pairs(bf16* __restrict__ dst, int w, int lane,
                                            const f32x4 acc[4][4])
{
    const int quad = lane >> 4, lx = lane & 15;
    const int c0 = w * 64 + 2 * lx;
#pragma unroll
    for (int mt = 0; mt < 4; mt++)
#pragma unroll
        for (int r = 0; r < 4; r++) {
            int row = mt * 16 + quad * 4 + r;
            *(unsigned int*)&dst[row * LDST + c0]      = pack2(acc[mt][0][r], acc[mt][1][r]);
            *(unsigned int*)&dst[row * LDST + c0 + 32] = pack2(acc[mt][2][r], acc[mt][3][r]);
        }
}

// ---------------- main fused head kernel ----------------
// Wave specialization: waves 0-3 = cls chain, waves 4-7 = reg chain (independent given h).
// Buffers: bufH holds h -> y1 -> y2 (in place), bufW holds x1 -> x2 (in place). 7 barriers total.
__global__ __launch_bounds__(512, 4) void head_kernel(
    const float* __restrict__ hs, const float* __restrict__ init_ref,
    const float* __restrict__ inter_ref,
    const bf16* __restrict__ cw1t, const bf16* __restrict__ cw2t,
    const bf16* __restrict__ rw1t, const bf16* __restrict__ rw2t,
    const bf16* __restrict__ cw3t, const bf16* __restrict__ rw3t,
    const float* __restrict__ cb1, const float* __restrict__ g1, const float* __restrict__ b1,
    const float* __restrict__ cb2, const float* __restrict__ g2, const float* __restrict__ b2,
    const float* __restrict__ cb3,
    const float* __restrict__ rb1, const float* __restrict__ rb2, const float* __restrict__ rb3,
    float* __restrict__ out)
{
    __shared__ __align__(16) bf16 bufH[ROWS * LDST];
    __shared__ __align__(16) bf16 bufW[ROWS * LDST];
    __shared__ float2 redC[4][ROWS];
    __shared__ float2 stat[ROWS];

    const int l    = blockIdx.y;
    const int row0 = blockIdx.x * ROWS;
    const int tid  = threadIdx.x;
    const int wave = tid >> 6;
    const int lane = tid & 63;
    const int quad = lane >> 4;
    const int lx   = lane & 15;
    const bool clsW = wave < 4;
    const int  w4   = wave & 3;

    // ---- stage h tile: hs[l][q][b][:] -> bufH[r][:] bf16, r = b*900 + q ----
    for (int ri = wave; ri < ROWS; ri += 8) {
        const int r = row0 + ri;
        const int b = r / 900;
        const int q = r - b * 900;
        const float4* src = (const float4*)(hs + (((size_t)l * 900 + q) * 32 + b) * 256);
        float4 vv = src[lane];
        union { bf16 h[4]; uint2 u; } pk;
        pk.h[0] = (bf16)vv.x; pk.h[1] = (bf16)vv.y; pk.h[2] = (bf16)vv.z; pk.h[3] = (bf16)vv.w;
        *(uint2*)&bufH[ri * LDST + lane * 4] = pk.u;
    }
    __syncthreads();                                         // S0: h staged

    f32x4 acc[4][4];

    // ===== phase A: cls1 | reg1 (both read bufH) =====
    gemm64w4(bufH, (clsW ? cw1t : rw1t) + (size_t)l * 65536, w4, lane, acc);
    if (clsW) ln_stats(acc, cb1 + l * 256, redC, w4, lane);
    else      bias_relu4(acc, rb1 + l * 256, w4, lane);
    __syncthreads();                                         // S1: bufH reads + redC retired
    if (tid < ROWS) stat_reduce(redC, stat, tid);
    if (!clsW) store_pairs(bufH, w4, lane, acc);             // y1 (in place over h)
    __syncthreads();                                         // S2: stat + y1 published
    if (clsW) {
        ln_norm(acc, g1 + l * 256, b1 + l * 256, stat, w4, lane);
        store_pairs(bufW, w4, lane, acc);                    // x1
    }
    __syncthreads();                                         // S3: x1 published

    // ===== phase B: cls2(bufW) | reg2(bufH) =====
    gemm64w4(clsW ? bufW : bufH, (clsW ? cw2t : rw2t) + (size_t)l * 65536, w4, lane, acc);
    if (clsW) ln_stats(acc, cb2 + l * 256, redC, w4, lane);
    else      bias_relu4(acc, rb2 + l * 256, w4, lane);
    __syncthreads();                                         // S4: phase-B reads + redC retired
    if (tid < ROWS) stat_reduce(redC, stat, tid);
    if (!clsW) store_pairs(bufH, w4, lane, acc);             // y2 (in place)
    __syncthreads();                                         // S5: stat + y2 published
    if (clsW) {
        ln_norm(acc, g2 + l * 256, b2 + l * 256, stat, w4, lane);
        store_pairs(bufW, w4, lane, acc);                    // x2 (in place; reads retired at S4)
    }
    __syncthreads();                                         // S6: x2 published

    // ===== phase C: cls3 (waves 0-3, bufW) | reg3 (waves 4-7, bufH) =====
    if (clsW) {
        f32x4 c = gemm16(bufW, cw3t + (size_t)l * 4096, w4 * 16, lane);
        if (lx < 10) {
            const float bv = cb3[l * 10 + lx];
#pragma unroll
            for (int r = 0; r < 4; r++) {
                int row = row0 + w4 * 16 + quad * 4 + r;
                out[((size_t)l * 28800 + row) * 10 + lx] = c[r] + bv;
            }
        }
    } else {
        f32x4 t = gemm16(bufH, rw3t + (size_t)l * 4096, w4 * 16, lane);
        if (lx < 10) {
            const float bv = rb3[l * 10 + lx];
            const float* refp = (l == 0) ? init_ref : (inter_ref + (size_t)(l - 1) * 28800 * 3);
#pragma unroll
            for (int r = 0; r < 4; r++) {
                int row = row0 + w4 * 16 + quad * 4 + r;
                float vv = t[r] + bv;
                float o;
                if (lx == 0 || lx == 1 || lx == 4) {
                    int rc = (lx == 4) ? 2 : lx;
                    float x = refp[(size_t)row * 3 + rc];
                    x = fminf(fmaxf(x, 0.f), 1.f);
                    float x1 = fmaxf(x, 1e-5f);
                    float x2 = fmaxf(1.f - x, 1e-5f);
                    float ris = logf(x1) - logf(x2);
                    float sg = 1.f / (1.f + expf(-(vv + ris)));
                    o = (lx == 4) ? (sg * 8.f - 5.f) : (sg * 102.4f - 51.2f);
                } else {
                    o = vv;
                }
                out[(size_t)(6 + l) * 28800 * 10 + (size_t)row * 10 + lx] = o;
            }
        }
    }
}

extern "C" void kernel_launch(void* const* d_in, const int* in_sizes, int n_in,
                              void* d_out, int out_size, void* d_ws, size_t ws_size,
                              hipStream_t stream)
{
    const float* hs        = (const float*)d_in[0];
    const float* init_ref  = (const float*)d_in[1];
    const float* inter_ref = (const float*)d_in[2];
    const float* cls_w1    = (const float*)d_in[3];
    const float* cls_b1    = (const float*)d_in[4];
    const float* ln1_g     = (const float*)d_in[5];
    const float* ln1_b     = (const float*)d_in[6];
    const float* cls_w2    = (const float*)d_in[7];
    const float* cls_b2    = (const float*)d_in[8];
    const float* ln2_g     = (const float*)d_in[9];
    const float* ln2_b     = (const float*)d_in[10];
    const float* cls_w3    = (const float*)d_in[11];
    const float* cls_b3    = (const float*)d_in[12];
    const float* reg_w1    = (const float*)d_in[13];
    const float* reg_b1    = (const float*)d_in[14];
    const float* reg_w2    = (const float*)d_in[15];
    const float* reg_b2    = (const float*)d_in[16];
    const float* reg_w3    = (const float*)d_in[17];
    const float* reg_b3    = (const float*)d_in[18];

    bf16* ws   = (bf16*)d_ws;
    bf16* cw1t = ws;                  // 4 contiguous 6*65536 regions
    bf16* cw2t = cw1t + 393216;
    bf16* rw1t = cw2t + 393216;
    bf16* rw2t = rw1t + 393216;
    bf16* cw3t = rw2t + 393216;       // 6*16*256
    bf16* rw3t = cw3t + 24576;

    transpose_all<<<dim3(4, 4, 24), 256, 0, stream>>>(cls_w1, cls_w2, reg_w1, reg_w2, cw1t);
    prep_small<<<192, 256, 0, stream>>>(cls_w3, reg_w3, cw3t, rw3t);

    head_kernel<<<dim3(450, 6), 512, 0, stream>>>(
        hs, init_ref, inter_ref,
        cw1t, cw2t, rw1t, rw2t, cw3t, rw3t,
        cls_b1, ln1_g, ln1_b, cls_b2, ln2_g, ln2_b, cls_b3,
        reg_b1, reg_b2, reg_b3, (float*)d_out);
}

// Round 2
// 535.307 us; speedup vs baseline: 1.1198x; 1.1198x over previous
//
#include <hip/hip_runtime.h>
#include <hip/hip_bf16.h>

typedef __bf16 bf16;
typedef __bf16 bf16x8 __attribute__((ext_vector_type(8)));
typedef float f32x4 __attribute__((ext_vector_type(4)));

#define ROWS 64
#define LDST 264  // 256 + 8 pad: row stride 528 B (16B-aligned)

// ---------------- prep: transpose all four [6][256][256] fp32 weight sets -> bf16 [N][K] ----------------
// N rows are stored PERMUTED within each 32-group: logical col c -> slot (c even ? c/2 : 16+c/2).
// With acc[4][2] (wave owns a 32-col slab), b[0] rows = slots 0-15 = even logical cols 2*lx,
// b[1] rows = slots 16-31 = odd logical cols 2*lx+1 -> activation store is a shuffle-free u32 pack
// and lands in STANDARD logical layout (no downstream K-permutation needed).
__global__ void transpose_all(const float* __restrict__ w0, const float* __restrict__ w1,
                              const float* __restrict__ w2, const float* __restrict__ w3,
                              bf16* __restrict__ out)
{
    __shared__ float tile[64][65];
    const int mz  = blockIdx.z;             // 0..23 = mat*6 + level
    const int mat = mz / 6;
    const float* srcs[4] = {w0, w1, w2, w3};
    const float* src = srcs[mat] + (size_t)(mz % 6) * 65536;
    bf16* dst = out + (size_t)mz * 65536;
    const int k0 = blockIdx.x * 64;
    const int n0 = blockIdx.y * 64;
    const int tx = threadIdx.x & 63, ty = threadIdx.x >> 6;
#pragma unroll
    for (int i = ty; i < 64; i += 4)
        tile[i][tx] = src[(size_t)(k0 + i) * 256 + n0 + tx];
    __syncthreads();
#pragma unroll
    for (int i = ty; i < 64; i += 4) {
        int n  = n0 + i;
        int o  = n & 31;
        int ns = (n & ~31) | ((o & 1) ? 16 + (o >> 1) : (o >> 1));
        dst[(size_t)ns * 256 + k0 + tx] = (bf16)tile[tx][i];
    }
}

// ---------------- prep: [6][256][10] -> [6][16][256] bf16, transposed + zero-padded (both w3s) ----------------
__global__ void prep_small(const float* __restrict__ cw3, const float* __restrict__ rw3,
                           bf16* __restrict__ outc, bf16* __restrict__ outr)
{
    int idx = blockIdx.x * 256 + threadIdx.x;  // 0..49151
    const float* w = (idx < 24576) ? cw3 : rw3;
    bf16* o = (idx < 24576) ? outc : outr;
    int j = (idx < 24576) ? idx : idx - 24576;
    int k = j & 255;
    int n = (j >> 8) & 15;
    int l = j >> 12;
    float v = (n < 10) ? w[((size_t)l * 256 + k) * 10 + n] : 0.0f;
    o[j] = (bf16)v;
}

// ---------------- helpers ----------------
__device__ __forceinline__ unsigned int pack2(float lo, float hi)
{
    union { bf16 h[2]; unsigned int u; } p;
    p.h[0] = (bf16)lo; p.h[1] = (bf16)hi;
    return p.u;
}

// VALU-pipe lane-reduce step (replaces ds_swizzle): x += x[dpp-permuted lane]
template<int CTRL>
__device__ __forceinline__ float dppadd(float x)
{
    int y = __builtin_amdgcn_update_dpp(0, __float_as_int(x), CTRL, 0xF, 0xF, true);
    return x + __int_as_float(y);
}
// full sum over a 16-lane DPP row (== the lx range of one quad)
__device__ __forceinline__ float dppsum16(float x)
{
    x = dppadd<0xB1>(x);   // quad_perm [1,0,3,2]  (xor 1)
    x = dppadd<0x4E>(x);   // quad_perm [2,3,0,1]  (xor 2)
    x = dppadd<0x141>(x);  // row_half_mirror      (join 4-groups)
    x = dppadd<0x140>(x);  // row_mirror           (join 8-halves)
    return x;
}

// 64x256 tile GEMM: acc[4 m-tiles][2 n-tiles], wave owns 32 stored-weight rows [wave*32, +32)
__device__ __forceinline__ void gemm64(const bf16* __restrict__ bufIn,
                                       const bf16* __restrict__ wt,
                                       int wave, int lane, f32x4 acc[4][2])
{
    const int quad = lane >> 4, lx = lane & 15;
    const int ncol0 = wave * 32;
#pragma unroll
    for (int mt = 0; mt < 4; mt++)
#pragma unroll
        for (int nt = 0; nt < 2; nt++)
            acc[mt][nt] = f32x4{0.f, 0.f, 0.f, 0.f};
#pragma unroll
    for (int kk = 0; kk < 8; kk++) {
        const int k0 = kk * 32 + quad * 8;
        bf16x8 a[4], b[2];
#pragma unroll
        for (int mt = 0; mt < 4; mt++)
            a[mt] = *(const bf16x8*)&bufIn[(mt * 16 + lx) * LDST + k0];
#pragma unroll
        for (int nt = 0; nt < 2; nt++)
            b[nt] = *(const bf16x8*)&wt[(ncol0 + nt * 16 + lx) * 256 + k0];
#pragma unroll
        for (int mt = 0; mt < 4; mt++)
#pragma unroll
            for (int nt = 0; nt < 2; nt++)
                acc[mt][nt] = __builtin_amdgcn_mfma_f32_16x16x32_bf16(a[mt], b[nt], acc[mt][nt], 0, 0, 0);
    }
}

// 16x256 @ 256x16 GEMM (final small layers; small weights NOT permuted)
__device__ __forceinline__ f32x4 gemm16(const bf16* __restrict__ bufIn,
                                        const bf16* __restrict__ wt,
                                        int mrow0, int lane)
{
    const int quad = lane >> 4, lx = lane & 15;
    f32x4 acc = f32x4{0.f, 0.f, 0.f, 0.f};
#pragma unroll
    for (int kk = 0; kk < 8; kk++) {
        const int k0 = kk * 32 + quad * 8;
        bf16x8 a = *(const bf16x8*)&bufIn[(mrow0 + lx) * LDST + k0];
        bf16x8 b = *(const bf16x8*)&wt[lx * 256 + k0];
        acc = __builtin_amdgcn_mfma_f32_16x16x32_bf16(a, b, acc, 0, 0, 0);
    }
    return acc;
}

// bias add in place + per-row (sum, sumsq) via DPP -> redC[wave]
__device__ __forceinline__ void ln_stats(f32x4 acc[4][2], const float* __restrict__ bias,
                                         float2 (*redC)[ROWS], int wave, int lane)
{
    const int quad = lane >> 4, lx = lane & 15;
    const float2 bv = *(const float2*)&bias[wave * 32 + 2 * lx];
#pragma unroll
    for (int mt = 0; mt < 4; mt++) {
        float s[4], ss[4];
#pragma unroll
        for (int r = 0; r < 4; r++) {
            float a0 = acc[mt][0][r] + bv.x;
            float a1 = acc[mt][1][r] + bv.y;
            acc[mt][0][r] = a0; acc[mt][1][r] = a1;
            s[r]  = a0 + a1;
            ss[r] = a0 * a0 + a1 * a1;
        }
#pragma unroll
        for (int r = 0; r < 4; r++) {
            s[r]  = dppsum16(s[r]);
            ss[r] = dppsum16(ss[r]);
        }
        if (lx == 0) {
#pragma unroll
            for (int r = 0; r < 4; r++)
                redC[wave][mt * 16 + quad * 4 + r] = make_float2(s[r], ss[r]);
        }
    }
}

// cross-wave stat reduce (tid < ROWS)
__device__ __forceinline__ void stat_reduce(const float2 (*redC)[ROWS], float2* __restrict__ stat, int tid)
{
    float sx = 0.f, sy = 0.f;
#pragma unroll
    for (int w = 0; w < 8; w++) { float2 t = redC[w][tid]; sx += t.x; sy += t.y; }
    float mean = sx * (1.f / 256.f);
    float var  = sy * (1.f / 256.f) - mean * mean;
    stat[tid] = make_float2(mean, rsqrtf(var + 1e-5f));
}

// normalize + relu in place
__device__ __forceinline__ void ln_norm(f32x4 acc[4][2],
                                        const float* __restrict__ g, const float* __restrict__ b,
                                        const float2* __restrict__ stat, int wave, int lane)
{
    const int quad = lane >> 4, lx = lane & 15;
    const int c0 = wave * 32 + 2 * lx;
    const float2 gv = *(const float2*)&g[c0];
    const float2 bv = *(const float2*)&b[c0];
#pragma unroll
    for (int mt = 0; mt < 4; mt++)
#pragma unroll
        for (int r = 0; r < 4; r++) {
            float2 st = stat[mt * 16 + quad * 4 + r];
            acc[mt][0][r] = fmaxf((acc[mt][0][r] - st.x) * st.y * gv.x + bv.x, 0.f);
            acc[mt][1][r] = fmaxf((acc[mt][1][r] - st.x) * st.y * gv.y + bv.y, 0.f);
        }
}

__device__ __forceinline__ void bias_relu(f32x4 acc[4][2], const float* __restrict__ bias,
                                          int wave, int lane)
{
    const int lx = lane & 15;
    const float2 bv = *(const float2*)&bias[wave * 32 + 2 * lx];
#pragma unroll
    for (int mt = 0; mt < 4; mt++)
#pragma unroll
        for (int r = 0; r < 4; r++) {
            acc[mt][0][r] = fmaxf(acc[mt][0][r] + bv.x, 0.f);
            acc[mt][1][r] = fmaxf(acc[mt][1][r] + bv.y, 0.f);
        }
}

// shuffle-free store: lane lx owns logical cols (2lx, 2lx+1) of its wave's 32-slab
__device__ __forceinline__ void store_pairs(bf16* __restrict__ dst, int wave, int lane,
                                            const f32x4 acc[4][2])
{
    const int quad = lane >> 4, lx = lane & 15;
    const int c0 = wave * 32 + 2 * lx;
#pragma unroll
    for (int mt = 0; mt < 4; mt++)
#pragma unroll
        for (int r = 0; r < 4; r++) {
            int row = mt * 16 + quad * 4 + r;
            *(unsigned int*)&dst[row * LDST + c0] = pack2(acc[mt][0][r], acc[mt][1][r]);
        }
}

// ---------------- main fused head kernel ----------------
// launch_bounds(512, 2): VGPR cap 128 (2 blocks/CU — which LDS enforces anyway). The 64-reg cap
// from (512,4) caused scratch spill (round-1 WRITE_SIZE 472 MB) and buys no occupancy.
__global__ __launch_bounds__(512, 2) void head_kernel(
    const float* __restrict__ hs, const float* __restrict__ init_ref,
    const float* __restrict__ inter_ref,
    const bf16* __restrict__ cw1t, const bf16* __restrict__ cw2t,
    const bf16* __restrict__ rw1t, const bf16* __restrict__ rw2t,
    const bf16* __restrict__ cw3t, const bf16* __restrict__ rw3t,
    const float* __restrict__ cb1, const float* __restrict__ g1, const float* __restrict__ b1,
    const float* __restrict__ cb2, const float* __restrict__ g2, const float* __restrict__ b2,
    const float* __restrict__ cb3,
    const float* __restrict__ rb1, const float* __restrict__ rb2, const float* __restrict__ rb3,
    float* __restrict__ out)
{
    __shared__ __align__(16) bf16 bufH[ROWS * LDST];   // h, live for whole block
    __shared__ __align__(16) bf16 bufW[ROWS * LDST];   // recycled: x1 -> x2 -> y1 -> y2
    __shared__ float2 redC[8][ROWS];
    __shared__ float2 stat[ROWS];

    const int l    = blockIdx.y;
    const int row0 = blockIdx.x * ROWS;
    const int tid  = threadIdx.x;
    const int wave = tid >> 6;
    const int lane = tid & 63;
    const int quad = lane >> 4;
    const int lx   = lane & 15;

    // ---- stage h tile: hs[l][q][b][:] -> bufH[r][:] bf16, r = b*900 + q ----
    for (int ri = wave; ri < ROWS; ri += 8) {
        const int r = row0 + ri;
        const int b = r / 900;
        const int q = r - b * 900;
        const float4* src = (const float4*)(hs + (((size_t)l * 900 + q) * 32 + b) * 256);
        float4 vv = src[lane];
        union { bf16 h[4]; uint2 u; } pk;
        pk.h[0] = (bf16)vv.x; pk.h[1] = (bf16)vv.y; pk.h[2] = (bf16)vv.z; pk.h[3] = (bf16)vv.w;
        *(uint2*)&bufH[ri * LDST + lane * 4] = pk.u;
    }
    __syncthreads();                                          // S0: h staged

    f32x4 acc[4][2];

    // ===== cls1: LN(h@cw1+cb1), relu -> bufW =====
    gemm64(bufH, cw1t + (size_t)l * 65536, wave, lane, acc);
    ln_stats(acc, cb1 + l * 256, redC, wave, lane);
    __syncthreads();                                          // S1: redC ready
    if (tid < ROWS) stat_reduce(redC, stat, tid);
    __syncthreads();                                          // S2: stat ready
    ln_norm(acc, g1 + l * 256, b1 + l * 256, stat, wave, lane);
    store_pairs(bufW, wave, lane, acc);
    __syncthreads();                                          // S3: x1 published

    // ===== cls2: LN(x1@cw2+cb2), relu -> bufW (in place; reads retired at S4) =====
    gemm64(bufW, cw2t + (size_t)l * 65536, wave, lane, acc);
    ln_stats(acc, cb2 + l * 256, redC, wave, lane);
    __syncthreads();                                          // S4: redC ready + bufW reads retired
    if (tid < ROWS) stat_reduce(redC, stat, tid);
    __syncthreads();                                          // S5: stat ready
    ln_norm(acc, g2 + l * 256, b2 + l * 256, stat, wave, lane);
    store_pairs(bufW, wave, lane, acc);
    __syncthreads();                                          // S6: x2 published

    // ===== cls3 (waves 0-3, reads bufW) overlapped with reg1 gemm (all waves, reads bufH) =====
    if (wave < 4) {
        f32x4 c = gemm16(bufW, cw3t + (size_t)l * 4096, wave * 16, lane);
        if (lx < 10) {
            const float bv = cb3[l * 10 + lx];
#pragma unroll
            for (int r = 0; r < 4; r++) {
                int row = row0 + wave * 16 + quad * 4 + r;
                out[((size_t)l * 28800 + row) * 10 + lx] = c[r] + bv;
            }
        }
    }
    gemm64(bufH, rw1t + (size_t)l * 65536, wave, lane, acc);
    __syncthreads();                                          // S7: cls3 bufW reads + reg1 bufH reads retired
    bias_relu(acc, rb1 + l * 256, wave, lane);
    store_pairs(bufW, wave, lane, acc);                       // y1
    __syncthreads();                                          // S8: y1 published

    // ===== reg2: relu(y1@rw2+rb2) -> bufW (in place) =====
    gemm64(bufW, rw2t + (size_t)l * 65536, wave, lane, acc);
    __syncthreads();                                          // S9: reads retired before in-place store
    bias_relu(acc, rb2 + l * 256, wave, lane);
    store_pairs(bufW, wave, lane, acc);                       // y2
    __syncthreads();                                          // S10: y2 published

    // ===== reg3 (waves 4-7): tmp = y2@rw3+rb3 -> coord transform -> out =====
    if (wave >= 4) {
        const int w2 = wave - 4;
        f32x4 t = gemm16(bufW, rw3t + (size_t)l * 4096, w2 * 16, lane);
        if (lx < 10) {
            const float bv = rb3[l * 10 + lx];
            const float* refp = (l == 0) ? init_ref : (inter_ref + (size_t)(l - 1) * 28800 * 3);
#pragma unroll
            for (int r = 0; r < 4; r++) {
                int row = row0 + w2 * 16 + quad * 4 + r;
                float vv = t[r] + bv;
                float o;
                if (lx == 0 || lx == 1 || lx == 4) {
                    int rc = (lx == 4) ? 2 : lx;
                    float x = refp[(size_t)row * 3 + rc];
                    x = fminf(fmaxf(x, 0.f), 1.f);
                    float x1 = fmaxf(x, 1e-5f);
                    float x2 = fmaxf(1.f - x, 1e-5f);
                    float ris = logf(x1) - logf(x2);
                    float sg = 1.f / (1.f + expf(-(vv + ris)));
                    o = (lx == 4) ? (sg * 8.f - 5.f) : (sg * 102.4f - 51.2f);
                } else {
                    o = vv;
                }
                out[(size_t)(6 + l) * 28800 * 10 + (size_t)row * 10 + lx] = o;
            }
        }
    }
}

extern "C" void kernel_launch(void* const* d_in, const int* in_sizes, int n_in,
                              void* d_out, int out_size, void* d_ws, size_t ws_size,
                              hipStream_t stream)
{
    const float* hs        = (const float*)d_in[0];
    const float* init_ref  = (const float*)d_in[1];
    const float* inter_ref = (const float*)d_in[2];
    const float* cls_w1    = (const float*)d_in[3];
    const float* cls_b1    = (const float*)d_in[4];
    const float* ln1_g     = (const float*)d_in[5];
    const float* ln1_b     = (const float*)d_in[6];
    const float* cls_w2    = (const float*)d_in[7];
    const float* cls_b2    = (const float*)d_in[8];
    const float* ln2_g     = (const float*)d_in[9];
    const float* ln2_b     = (const float*)d_in[10];
    const float* cls_w3    = (const float*)d_in[11];
    const float* cls_b3    = (const float*)d_in[12];
    const float* reg_w1    = (const float*)d_in[13];
    const float* reg_b1    = (const float*)d_in[14];
    const float* reg_w2    = (const float*)d_in[15];
    const float* reg_b2    = (const float*)d_in[16];
    const float* reg_w3    = (const float*)d_in[17];
    const float* reg_b3    = (const float*)d_in[18];

    bf16* ws   = (bf16*)d_ws;
    bf16* cw1t = ws;                  // 4 contiguous 6*65536 regions
    bf16* cw2t = cw1t + 393216;
    bf16* rw1t = cw2t + 393216;
    bf16* rw2t = rw1t + 393216;
    bf16* cw3t = rw2t + 393216;       // 6*16*256
    bf16* rw3t = cw3t + 24576;

    transpose_all<<<dim3(4, 4, 24), 256, 0, stream>>>(cls_w1, cls_w2, reg_w1, reg_w2, cw1t);
    prep_small<<<192, 256, 0, stream>>>(cls_w3, reg_w3, cw3t, rw3t);

    head_kernel<<<dim3(450, 6), 512, 0, stream>>>(
        hs, init_ref, inter_ref,
        cw1t, cw2t, rw1t, rw2t, cw3t, rw3t,
        cls_b1, ln1_g, ln1_b, cls_b2, ln2_g, ln2_b, cls_b3,
        reg_b1, reg_b2, reg_b3, (float*)d_out);
}

// Round 3
// 526.980 us; speedup vs baseline: 1.1375x; 1.0158x over previous
//
#include <hip/hip_runtime.h>
#include <hip/hip_bf16.h>

typedef __bf16 bf16;
typedef __bf16 bf16x8 __attribute__((ext_vector_type(8)));
typedef float f32x4 __attribute__((ext_vector_type(4)));

#define ROWS 48   // 3 blocks/CU: LDS/block = 53760 B (was 72192 at ROWS=64 -> 2 blocks)
#define LDST 264  // 256 + 8 pad: row stride 528 B (16B-aligned)

// ---------------- prep: transpose all four [6][256][256] fp32 weight sets -> bf16 [N][K] ----------------
// N rows are stored PERMUTED within each 32-group: logical col c -> slot (c even ? c/2 : 16+c/2).
// With acc[.][2] (wave owns a 32-col slab), b[0] rows = slots 0-15 = even logical cols 2*lx,
// b[1] rows = slots 16-31 = odd logical cols 2*lx+1 -> activation store is a shuffle-free u32 pack
// and lands in STANDARD logical layout (no downstream K-permutation needed).
__global__ void transpose_all(const float* __restrict__ w0, const float* __restrict__ w1,
                              const float* __restrict__ w2, const float* __restrict__ w3,
                              bf16* __restrict__ out)
{
    __shared__ float tile[64][65];
    const int mz  = blockIdx.z;             // 0..23 = mat*6 + level
    const int mat = mz / 6;
    const float* srcs[4] = {w0, w1, w2, w3};
    const float* src = srcs[mat] + (size_t)(mz % 6) * 65536;
    bf16* dst = out + (size_t)mz * 65536;
    const int k0 = blockIdx.x * 64;
    const int n0 = blockIdx.y * 64;
    const int tx = threadIdx.x & 63, ty = threadIdx.x >> 6;
#pragma unroll
    for (int i = ty; i < 64; i += 4)
        tile[i][tx] = src[(size_t)(k0 + i) * 256 + n0 + tx];
    __syncthreads();
#pragma unroll
    for (int i = ty; i < 64; i += 4) {
        int n  = n0 + i;
        int o  = n & 31;
        int ns = (n & ~31) | ((o & 1) ? 16 + (o >> 1) : (o >> 1));
        dst[(size_t)ns * 256 + k0 + tx] = (bf16)tile[tx][i];
    }
}

// ---------------- prep: [6][256][10] -> [6][16][256] bf16, transposed + zero-padded (both w3s) ----------------
__global__ void prep_small(const float* __restrict__ cw3, const float* __restrict__ rw3,
                           bf16* __restrict__ outc, bf16* __restrict__ outr)
{
    int idx = blockIdx.x * 256 + threadIdx.x;  // 0..49151
    const float* w = (idx < 24576) ? cw3 : rw3;
    bf16* o = (idx < 24576) ? outc : outr;
    int j = (idx < 24576) ? idx : idx - 24576;
    int k = j & 255;
    int n = (j >> 8) & 15;
    int l = j >> 12;
    float v = (n < 10) ? w[((size_t)l * 256 + k) * 10 + n] : 0.0f;
    o[j] = (bf16)v;
}

// ---------------- helpers ----------------
__device__ __forceinline__ unsigned int pack2(float lo, float hi)
{
    union { bf16 h[2]; unsigned int u; } p;
    p.h[0] = (bf16)lo; p.h[1] = (bf16)hi;
    return p.u;
}

// VALU-pipe lane-reduce step (replaces ds_swizzle): x += x[dpp-permuted lane]
template<int CTRL>
__device__ __forceinline__ float dppadd(float x)
{
    int y = __builtin_amdgcn_update_dpp(0, __float_as_int(x), CTRL, 0xF, 0xF, true);
    return x + __int_as_float(y);
}
// full sum over a 16-lane DPP row (== the lx range of one quad)
__device__ __forceinline__ float dppsum16(float x)
{
    x = dppadd<0xB1>(x);   // quad_perm [1,0,3,2]  (xor 1)
    x = dppadd<0x4E>(x);   // quad_perm [2,3,0,1]  (xor 2)
    x = dppadd<0x141>(x);  // row_half_mirror      (join 4-groups)
    x = dppadd<0x140>(x);  // row_mirror           (join 8-halves)
    return x;
}

// 48x256 tile GEMM: acc[3 m-tiles][2 n-tiles], wave owns 32 stored-weight rows [wave*32, +32)
__device__ __forceinline__ void gemm48(const bf16* __restrict__ bufIn,
                                       const bf16* __restrict__ wt,
                                       int wave, int lane, f32x4 acc[3][2])
{
    const int quad = lane >> 4, lx = lane & 15;
    const int ncol0 = wave * 32;
#pragma unroll
    for (int mt = 0; mt < 3; mt++)
#pragma unroll
        for (int nt = 0; nt < 2; nt++)
            acc[mt][nt] = f32x4{0.f, 0.f, 0.f, 0.f};
#pragma unroll
    for (int kk = 0; kk < 8; kk++) {
        const int k0 = kk * 32 + quad * 8;
        bf16x8 a[3], b[2];
#pragma unroll
        for (int mt = 0; mt < 3; mt++)
            a[mt] = *(const bf16x8*)&bufIn[(mt * 16 + lx) * LDST + k0];
#pragma unroll
        for (int nt = 0; nt < 2; nt++)
            b[nt] = *(const bf16x8*)&wt[(ncol0 + nt * 16 + lx) * 256 + k0];
#pragma unroll
        for (int mt = 0; mt < 3; mt++)
#pragma unroll
            for (int nt = 0; nt < 2; nt++)
                acc[mt][nt] = __builtin_amdgcn_mfma_f32_16x16x32_bf16(a[mt], b[nt], acc[mt][nt], 0, 0, 0);
    }
}

// 16x256 @ 256x16 GEMM (final small layers; small weights NOT permuted)
__device__ __forceinline__ f32x4 gemm16(const bf16* __restrict__ bufIn,
                                        const bf16* __restrict__ wt,
                                        int mrow0, int lane)
{
    const int quad = lane >> 4, lx = lane & 15;
    f32x4 acc = f32x4{0.f, 0.f, 0.f, 0.f};
#pragma unroll
    for (int kk = 0; kk < 8; kk++) {
        const int k0 = kk * 32 + quad * 8;
        bf16x8 a = *(const bf16x8*)&bufIn[(mrow0 + lx) * LDST + k0];
        bf16x8 b = *(const bf16x8*)&wt[lx * 256 + k0];
        acc = __builtin_amdgcn_mfma_f32_16x16x32_bf16(a, b, acc, 0, 0, 0);
    }
    return acc;
}

// bias add in place + per-row (sum, sumsq) via DPP -> redC[wave]
__device__ __forceinline__ void ln_stats(f32x4 acc[3][2], const float* __restrict__ bias,
                                         float2 (*redC)[ROWS], int wave, int lane)
{
    const int quad = lane >> 4, lx = lane & 15;
    const float2 bv = *(const float2*)&bias[wave * 32 + 2 * lx];
#pragma unroll
    for (int mt = 0; mt < 3; mt++) {
        float s[4], ss[4];
#pragma unroll
        for (int r = 0; r < 4; r++) {
            float a0 = acc[mt][0][r] + bv.x;
            float a1 = acc[mt][1][r] + bv.y;
            acc[mt][0][r] = a0; acc[mt][1][r] = a1;
            s[r]  = a0 + a1;
            ss[r] = a0 * a0 + a1 * a1;
        }
#pragma unroll
        for (int r = 0; r < 4; r++) {
            s[r]  = dppsum16(s[r]);
            ss[r] = dppsum16(ss[r]);
        }
        if (lx == 0) {
#pragma unroll
            for (int r = 0; r < 4; r++)
                redC[wave][mt * 16 + quad * 4 + r] = make_float2(s[r], ss[r]);
        }
    }
}

// cross-wave stat reduce (tid < ROWS). stat aliases redC[0] (write-after-read, same thread).
__device__ __forceinline__ void stat_reduce(float2 (*redC)[ROWS], int tid)
{
    float sx = 0.f, sy = 0.f;
#pragma unroll
    for (int w = 0; w < 8; w++) { float2 t = redC[w][tid]; sx += t.x; sy += t.y; }
    float mean = sx * (1.f / 256.f);
    float var  = sy * (1.f / 256.f) - mean * mean;
    redC[0][tid] = make_float2(mean, rsqrtf(var + 1e-5f));
}

// normalize + relu in place (stat = redC[0])
__device__ __forceinline__ void ln_norm(f32x4 acc[3][2],
                                        const float* __restrict__ g, const float* __restrict__ b,
                                        const float2* __restrict__ stat, int wave, int lane)
{
    const int quad = lane >> 4, lx = lane & 15;
    const int c0 = wave * 32 + 2 * lx;
    const float2 gv = *(const float2*)&g[c0];
    const float2 bv = *(const float2*)&b[c0];
#pragma unroll
    for (int mt = 0; mt < 3; mt++)
#pragma unroll
        for (int r = 0; r < 4; r++) {
            float2 st = stat[mt * 16 + quad * 4 + r];
            acc[mt][0][r] = fmaxf((acc[mt][0][r] - st.x) * st.y * gv.x + bv.x, 0.f);
            acc[mt][1][r] = fmaxf((acc[mt][1][r] - st.x) * st.y * gv.y + bv.y, 0.f);
        }
}

__device__ __forceinline__ void bias_relu(f32x4 acc[3][2], const float* __restrict__ bias,
                                          int wave, int lane)
{
    const int lx = lane & 15;
    const float2 bv = *(const float2*)&bias[wave * 32 + 2 * lx];
#pragma unroll
    for (int mt = 0; mt < 3; mt++)
#pragma unroll
        for (int r = 0; r < 4; r++) {
            acc[mt][0][r] = fmaxf(acc[mt][0][r] + bv.x, 0.f);
            acc[mt][1][r] = fmaxf(acc[mt][1][r] + bv.y, 0.f);
        }
}

// shuffle-free store: lane lx owns logical cols (2lx, 2lx+1) of its wave's 32-slab
__device__ __forceinline__ void store_pairs(bf16* __restrict__ dst, int wave, int lane,
                                            const f32x4 acc[3][2])
{
    const int quad = lane >> 4, lx = lane & 15;
    const int c0 = wave * 32 + 2 * lx;
#pragma unroll
    for (int mt = 0; mt < 3; mt++)
#pragma unroll
        for (int r = 0; r < 4; r++) {
            int row = mt * 16 + quad * 4 + r;
            *(unsigned int*)&dst[row * LDST + c0] = pack2(acc[mt][0][r], acc[mt][1][r]);
        }
}

// ---------------- main fused head kernel ----------------
// launch_bounds arg2 = min WORKGROUPS/CU on this toolchain (measured: (512,4)->cap 64, (512,2)->cap 128).
// (512,3) -> VGPR cap 85; LDS 53760 B -> 3 blocks/CU (161.3 KB of 160 KiB pool).
__global__ __launch_bounds__(512, 3) void head_kernel(
    const float* __restrict__ hs, const float* __restrict__ init_ref,
    const float* __restrict__ inter_ref,
    const bf16* __restrict__ cw1t, const bf16* __restrict__ cw2t,
    const bf16* __restrict__ rw1t, const bf16* __restrict__ rw2t,
    const bf16* __restrict__ cw3t, const bf16* __restrict__ rw3t,
    const float* __restrict__ cb1, const float* __restrict__ g1, const float* __restrict__ b1,
    const float* __restrict__ cb2, const float* __restrict__ g2, const float* __restrict__ b2,
    const float* __restrict__ cb3,
    const float* __restrict__ rb1, const float* __restrict__ rb2, const float* __restrict__ rb3,
    float* __restrict__ out)
{
    __shared__ __align__(16) bf16 bufH[ROWS * LDST];   // h, live until reg1 completes
    __shared__ __align__(16) bf16 bufW[ROWS * LDST];   // recycled: x1 -> x2 -> y1 -> y2
    __shared__ float2 redC[8][ROWS];                   // redC[0] doubles as stat after reduce

    const int l    = blockIdx.y;
    const int row0 = blockIdx.x * ROWS;
    const int tid  = threadIdx.x;
    const int wave = tid >> 6;
    const int lane = tid & 63;
    const int quad = lane >> 4;
    const int lx   = lane & 15;

    // ---- stage h tile: hs[l][q][b][:] -> bufH[r][:] bf16, r = b*900 + q ----
    for (int ri = wave; ri < ROWS; ri += 8) {
        const int r = row0 + ri;
        const int b = r / 900;
        const int q = r - b * 900;
        const float4* src = (const float4*)(hs + (((size_t)l * 900 + q) * 32 + b) * 256);
        float4 vv = src[lane];
        union { bf16 h[4]; uint2 u; } pk;
        pk.h[0] = (bf16)vv.x; pk.h[1] = (bf16)vv.y; pk.h[2] = (bf16)vv.z; pk.h[3] = (bf16)vv.w;
        *(uint2*)&bufH[ri * LDST + lane * 4] = pk.u;
    }
    __syncthreads();                                          // S0: h staged

    f32x4 acc[3][2];

    // ===== cls1: LN(h@cw1+cb1), relu -> bufW =====
    gemm48(bufH, cw1t + (size_t)l * 65536, wave, lane, acc);
    ln_stats(acc, cb1 + l * 256, redC, wave, lane);
    __syncthreads();                                          // S1: redC ready
    if (tid < ROWS) stat_reduce(redC, tid);
    __syncthreads();                                          // S2: stat ready
    ln_norm(acc, g1 + l * 256, b1 + l * 256, redC[0], wave, lane);
    store_pairs(bufW, wave, lane, acc);
    __syncthreads();                                          // S3: x1 published

    // ===== cls2: LN(x1@cw2+cb2), relu -> bufW (in place; reads retired at S4) =====
    gemm48(bufW, cw2t + (size_t)l * 65536, wave, lane, acc);
    ln_stats(acc, cb2 + l * 256, redC, wave, lane);
    __syncthreads();                                          // S4: redC ready + bufW reads retired
    if (tid < ROWS) stat_reduce(redC, tid);
    __syncthreads();                                          // S5: stat ready
    ln_norm(acc, g2 + l * 256, b2 + l * 256, redC[0], wave, lane);
    store_pairs(bufW, wave, lane, acc);
    __syncthreads();                                          // S6: x2 published

    // ===== cls3 (waves 0-2, reads bufW) overlapped with reg1 gemm (all waves, reads bufH) =====
    if (wave < 3) {
        f32x4 c = gemm16(bufW, cw3t + (size_t)l * 4096, wave * 16, lane);
        if (lx < 10) {
            const float bv = cb3[l * 10 + lx];
#pragma unroll
            for (int r = 0; r < 4; r++) {
                int row = row0 + wave * 16 + quad * 4 + r;
                out[((size_t)l * 28800 + row) * 10 + lx] = c[r] + bv;
            }
        }
    }
    gemm48(bufH, rw1t + (size_t)l * 65536, wave, lane, acc);
    __syncthreads();                                          // S7: cls3 bufW reads + reg1 bufH reads retired
    bias_relu(acc, rb1 + l * 256, wave, lane);
    store_pairs(bufW, wave, lane, acc);                       // y1
    __syncthreads();                                          // S8: y1 published

    // ===== reg2: relu(y1@rw2+rb2) -> bufW (in place) =====
    gemm48(bufW, rw2t + (size_t)l * 65536, wave, lane, acc);
    __syncthreads();                                          // S9: reads retired before in-place store
    bias_relu(acc, rb2 + l * 256, wave, lane);
    store_pairs(bufW, wave, lane, acc);                       // y2
    __syncthreads();                                          // S10: y2 published

    // ===== reg3 (waves 4-6): tmp = y2@rw3+rb3 -> coord transform -> out =====
    if (wave >= 4 && wave < 7) {
        const int w2 = wave - 4;
        f32x4 t = gemm16(bufW, rw3t + (size_t)l * 4096, w2 * 16, lane);
        if (lx < 10) {
            const float bv = rb3[l * 10 + lx];
            const float* refp = (l == 0) ? init_ref : (inter_ref + (size_t)(l - 1) * 28800 * 3);
#pragma unroll
            for (int r = 0; r < 4; r++) {
                int row = row0 + w2 * 16 + quad * 4 + r;
                float vv = t[r] + bv;
                float o;
                if (lx == 0 || lx == 1 || lx == 4) {
                    int rc = (lx == 4) ? 2 : lx;
                    float x = refp[(size_t)row * 3 + rc];
                    x = fminf(fmaxf(x, 0.f), 1.f);
                    float x1 = fmaxf(x, 1e-5f);
                    float x2 = fmaxf(1.f - x, 1e-5f);
                    float ris = logf(x1) - logf(x2);
                    float sg = 1.f / (1.f + expf(-(vv + ris)));
                    o = (lx == 4) ? (sg * 8.f - 5.f) : (sg * 102.4f - 51.2f);
                } else {
                    o = vv;
                }
                out[(size_t)(6 + l) * 28800 * 10 + (size_t)row * 10 + lx] = o;
            }
        }
    }
}

extern "C" void kernel_launch(void* const* d_in, const int* in_sizes, int n_in,
                              void* d_out, int out_size, void* d_ws, size_t ws_size,
                              hipStream_t stream)
{
    const float* hs        = (const float*)d_in[0];
    const float* init_ref  = (const float*)d_in[1];
    const float* inter_ref = (const float*)d_in[2];
    const float* cls_w1    = (const float*)d_in[3];
    const float* cls_b1    = (const float*)d_in[4];
    const float* ln1_g     = (const float*)d_in[5];
    const float* ln1_b     = (const float*)d_in[6];
    const float* cls_w2    = (const float*)d_in[7];
    const float* cls_b2    = (const float*)d_in[8];
    const float* ln2_g     = (const float*)d_in[9];
    const float* ln2_b     = (const float*)d_in[10];
    const float* cls_w3    = (const float*)d_in[11];
    const float* cls_b3    = (const float*)d_in[12];
    const float* reg_w1    = (const float*)d_in[13];
    const float* reg_b1    = (const float*)d_in[14];
    const float* reg_w2    = (const float*)d_in[15];
    const float* reg_b2    = (const float*)d_in[16];
    const float* reg_w3    = (const float*)d_in[17];
    const float* reg_b3    = (const float*)d_in[18];

    bf16* ws   = (bf16*)d_ws;
    bf16* cw1t = ws;                  // 4 contiguous 6*65536 regions
    bf16* cw2t = cw1t + 393216;
    bf16* rw1t = cw2t + 393216;
    bf16* rw2t = rw1t + 393216;
    bf16* cw3t = rw2t + 393216;       // 6*16*256
    bf16* rw3t = cw3t + 24576;

    transpose_all<<<dim3(4, 4, 24), 256, 0, stream>>>(cls_w1, cls_w2, reg_w1, reg_w2, cw1t);
    prep_small<<<192, 256, 0, stream>>>(cls_w3, reg_w3, cw3t, rw3t);

    head_kernel<<<dim3(600, 6), 512, 0, stream>>>(
        hs, init_ref, inter_ref,
        cw1t, cw2t, rw1t, rw2t, cw3t, rw3t,
        cls_b1, ln1_g, ln1_b, cls_b2, ln2_g, ln2_b, cls_b3,
        reg_b1, reg_b2, reg_b3, (float*)d_out);
}

// Round 4
// 507.092 us; speedup vs baseline: 1.1821x; 1.0392x over previous
//
#include <hip/hip_runtime.h>
#include <hip/hip_bf16.h>

typedef __bf16 bf16;
typedef __bf16 bf16x8 __attribute__((ext_vector_type(8)));
typedef float f32x4 __attribute__((ext_vector_type(4)));

#define LDST 264   // per-wave slab row stride in bf16 elems (16 rows x 264)

// ---------------- prep: transpose big weights -> bf16, PERMUTED slots, K-OUTER packed ----------------
// Logical col c -> slot ns = (c&~31) | (c odd ? 16+(c&31)/2 : (c&31)/2)   (permute within 32-groups)
// Storage: wpk[k>>3][slot][k&7]  (elem idx = (k>>3)*2048 + slot*8 + (k&7))
// -> for a given kk,quad the 16 B-frags of a wave are contiguous 16 B x 256 slots (imm-offset addressing,
//    256B-coalesced, all 8 waves hit the same 16KB region -> L1 reuse).
__global__ void transpose_all(const float* __restrict__ w0, const float* __restrict__ w1,
                              const float* __restrict__ w2, const float* __restrict__ w3,
                              bf16* __restrict__ out)
{
    __shared__ float tile[64][65];
    const int mz  = blockIdx.z;             // 0..23 = mat*6 + level
    const int mat = mz / 6;
    const float* srcs[4] = {w0, w1, w2, w3};
    const float* src = srcs[mat] + (size_t)(mz % 6) * 65536;
    bf16* dst = out + (size_t)mz * 65536;
    const int k0 = blockIdx.x * 64;
    const int n0 = blockIdx.y * 64;
    const int tx = threadIdx.x & 63, ty = threadIdx.x >> 6;
#pragma unroll
    for (int i = ty; i < 64; i += 4)
        tile[i][tx] = src[(size_t)(k0 + i) * 256 + n0 + tx];
    __syncthreads();
#pragma unroll
    for (int i = ty; i < 64; i += 4) {
        int n  = n0 + i;
        int o  = n & 31;
        int ns = (n & ~31) | ((o & 1) ? 16 + (o >> 1) : (o >> 1));
        int k  = k0 + tx;
        dst[(size_t)(k >> 3) * 2048 + ns * 8 + (k & 7)] = (bf16)tile[tx][i];
    }
}

// ---------------- prep: [6][256][10] -> [6][16][256] bf16, transposed + zero-padded (both w3s) ----------------
__global__ void prep_small(const float* __restrict__ cw3, const float* __restrict__ rw3,
                           bf16* __restrict__ outc, bf16* __restrict__ outr)
{
    int idx = blockIdx.x * 256 + threadIdx.x;  // 0..49151
    const float* w = (idx < 24576) ? cw3 : rw3;
    bf16* o = (idx < 24576) ? outc : outr;
    int j = (idx < 24576) ? idx : idx - 24576;
    int k = j & 255;
    int n = (j >> 8) & 15;
    int l = j >> 12;
    float v = (n < 10) ? w[((size_t)l * 256 + k) * 10 + n] : 0.0f;
    o[j] = (bf16)v;
}

// ---------------- helpers ----------------
__device__ __forceinline__ unsigned int pack2(float lo, float hi)
{
    union { bf16 h[2]; unsigned int u; } p;
    p.h[0] = (bf16)lo; p.h[1] = (bf16)hi;
    return p.u;
}

__device__ __forceinline__ bf16x8 cvt8(float4 a, float4 b)
{
    union { bf16 h[8]; bf16x8 v; } u;
    u.h[0] = (bf16)a.x; u.h[1] = (bf16)a.y; u.h[2] = (bf16)a.z; u.h[3] = (bf16)a.w;
    u.h[4] = (bf16)b.x; u.h[5] = (bf16)b.y; u.h[6] = (bf16)b.z; u.h[7] = (bf16)b.w;
    return u.v;
}

// VALU-pipe lane-reduce step: x += x[dpp-permuted lane]
template<int CTRL>
__device__ __forceinline__ float dppadd(float x)
{
    int y = __builtin_amdgcn_update_dpp(0, __float_as_int(x), CTRL, 0xF, 0xF, true);
    return x + __int_as_float(y);
}
// full sum across the 16-lane DPP row (= one quad); result broadcast to all 16 lanes
__device__ __forceinline__ float dppsum16(float x)
{
    x = dppadd<0xB1>(x);   // quad_perm [1,0,3,2]
    x = dppadd<0x4E>(x);   // quad_perm [2,3,0,1]
    x = dppadd<0x141>(x);  // row_half_mirror
    x = dppadd<0x140>(x);  // row_mirror
    return x;
}

// full-row GEMM, A from registers: 16 rows x 256 cols per wave, acc[16] (nt pairs = even/odd cols)
__device__ __forceinline__ void gemmFR(const bf16x8 aH[8], const bf16* __restrict__ wt,
                                       int lane, f32x4 acc[16])
{
    const int quad = lane >> 4, lx = lane & 15;
#pragma unroll
    for (int nt = 0; nt < 16; nt++) acc[nt] = f32x4{0.f, 0.f, 0.f, 0.f};
    // byte layout of wt: kk*16384 + quad*4096 + nt*256 + lx*16
    const bf16* base = wt + (size_t)quad * 2048 + lx * 8;
#pragma unroll
    for (int kk = 0; kk < 8; kk++) {
        const bf16* bp = base + kk * 8192;
        bf16x8 bfrag[16];
#pragma unroll
        for (int nt = 0; nt < 16; nt++)
            bfrag[nt] = *(const bf16x8*)(bp + nt * 128);
#pragma unroll
        for (int nt = 0; nt < 16; nt++)
            acc[nt] = __builtin_amdgcn_mfma_f32_16x16x32_bf16(aH[kk], bfrag[nt], acc[nt], 0, 0, 0);
    }
}

// full-row GEMM, A from per-wave LDS slab
__device__ __forceinline__ void gemmFR_lds(const bf16* slab, const bf16* __restrict__ wt,
                                           int lane, f32x4 acc[16])
{
    const int quad = lane >> 4, lx = lane & 15;
#pragma unroll
    for (int nt = 0; nt < 16; nt++) acc[nt] = f32x4{0.f, 0.f, 0.f, 0.f};
    const bf16* base = wt + (size_t)quad * 2048 + lx * 8;
#pragma unroll
    for (int kk = 0; kk < 8; kk++) {
        bf16x8 a = *(const bf16x8*)&slab[lx * LDST + kk * 32 + quad * 8];
        const bf16* bp = base + kk * 8192;
        bf16x8 bfrag[16];
#pragma unroll
        for (int nt = 0; nt < 16; nt++)
            bfrag[nt] = *(const bf16x8*)(bp + nt * 128);
#pragma unroll
        for (int nt = 0; nt < 16; nt++)
            acc[nt] = __builtin_amdgcn_mfma_f32_16x16x32_bf16(a, bfrag[nt], acc[nt], 0, 0, 0);
    }
}

// 16x256 @ 256x16 (small layers; weights [slot][256], unpermuted)
__device__ __forceinline__ f32x4 gemm16(const bf16* slab, const bf16* __restrict__ wt, int lane)
{
    const int quad = lane >> 4, lx = lane & 15;
    f32x4 acc = f32x4{0.f, 0.f, 0.f, 0.f};
#pragma unroll
    for (int kk = 0; kk < 8; kk++) {
        const int k0 = kk * 32 + quad * 8;
        bf16x8 a = *(const bf16x8*)&slab[lx * LDST + k0];
        bf16x8 b = *(const bf16x8*)&wt[lx * 256 + k0];
        acc = __builtin_amdgcn_mfma_f32_16x16x32_bf16(a, b, acc, 0, 0, 0);
    }
    return acc;
}

// wave-local LN: bias add, stats via in-reg nt-sum + dppsum16 (stats land in the owning lanes), norm+relu
__device__ __forceinline__ void ln_epi(f32x4 acc[16], const float* __restrict__ bias,
                                       const float* __restrict__ g, const float* __restrict__ bb,
                                       int lane)
{
    const int lx = lane & 15;
    float s[4] = {0.f, 0.f, 0.f, 0.f}, ss[4] = {0.f, 0.f, 0.f, 0.f};
#pragma unroll
    for (int sg = 0; sg < 8; sg++) {
        const float2 bv = *(const float2*)&bias[sg * 32 + 2 * lx];
#pragma unroll
        for (int r = 0; r < 4; r++) {
            float a0 = acc[2 * sg][r] + bv.x;
            float a1 = acc[2 * sg + 1][r] + bv.y;
            acc[2 * sg][r] = a0; acc[2 * sg + 1][r] = a1;
            s[r]  += a0 + a1;
            ss[r] += a0 * a0 + a1 * a1;
        }
    }
    float mean[4], rstd[4];
#pragma unroll
    for (int r = 0; r < 4; r++) {
        float st  = dppsum16(s[r]);
        float sst = dppsum16(ss[r]);
        mean[r] = st * (1.f / 256.f);
        float var = sst * (1.f / 256.f) - mean[r] * mean[r];
        rstd[r] = rsqrtf(var + 1e-5f);
    }
#pragma unroll
    for (int sg = 0; sg < 8; sg++) {
        const float2 gv  = *(const float2*)&g[sg * 32 + 2 * lx];
        const float2 bv2 = *(const float2*)&bb[sg * 32 + 2 * lx];
#pragma unroll
        for (int r = 0; r < 4; r++) {
            acc[2 * sg][r]     = fmaxf((acc[2 * sg][r]     - mean[r]) * rstd[r] * gv.x + bv2.x, 0.f);
            acc[2 * sg + 1][r] = fmaxf((acc[2 * sg + 1][r] - mean[r]) * rstd[r] * gv.y + bv2.y, 0.f);
        }
    }
}

__device__ __forceinline__ void bias_epi(f32x4 acc[16], const float* __restrict__ bias, int lane)
{
    const int lx = lane & 15;
#pragma unroll
    for (int sg = 0; sg < 8; sg++) {
        const float2 bv = *(const float2*)&bias[sg * 32 + 2 * lx];
#pragma unroll
        for (int r = 0; r < 4; r++) {
            acc[2 * sg][r]     = fmaxf(acc[2 * sg][r]     + bv.x, 0.f);
            acc[2 * sg + 1][r] = fmaxf(acc[2 * sg + 1][r] + bv.y, 0.f);
        }
    }
}

// shuffle-free slab store: lane lx owns logical cols (32s+2lx, 32s+2lx+1); wave-lockstep + lgkmcnt
// ordering makes write->read and in-place reuse safe without any barrier.
__device__ __forceinline__ void store_slab(bf16* slab, int lane, const f32x4 acc[16])
{
    const int quad = lane >> 4, lx = lane & 15;
#pragma unroll
    for (int sg = 0; sg < 8; sg++)
#pragma unroll
        for (int r = 0; r < 4; r++)
            *(unsigned int*)&slab[(quad * 4 + r) * LDST + sg * 32 + 2 * lx] =
                pack2(acc[2 * sg][r], acc[2 * sg + 1][r]);
}

// ---------------- main fused head kernel: ZERO block barriers, one 16-row slice per wave ----------------
__global__ __launch_bounds__(256, 2) void head_kernel(
    const float* __restrict__ hs, const float* __restrict__ init_ref,
    const float* __restrict__ inter_ref,
    const bf16* __restrict__ cw1t, const bf16* __restrict__ cw2t,
    const bf16* __restrict__ rw1t, const bf16* __restrict__ rw2t,
    const bf16* __restrict__ cw3t, const bf16* __restrict__ rw3t,
    const float* __restrict__ cb1, const float* __restrict__ g1, const float* __restrict__ b1,
    const float* __restrict__ cb2, const float* __restrict__ g2, const float* __restrict__ b2,
    const float* __restrict__ cb3,
    const float* __restrict__ rb1, const float* __restrict__ rb2, const float* __restrict__ rb3,
    float* __restrict__ out)
{
    __shared__ __align__(16) bf16 slabs[4][16 * LDST];   // 33.8 KB/block, private per wave

    const int l    = blockIdx.y;
    const int tid  = threadIdx.x;
    const int wave = tid >> 6;
    const int lane = tid & 63;
    const int quad = lane >> 4;
    const int lx   = lane & 15;
    const int row0 = blockIdx.x * 64 + wave * 16;        // wave's first logical row (within level l)
    bf16* slab = slabs[wave];

    // ---- h A-frags: global -> registers (32 VGPRs), reused by cls1 AND reg1; no LDS, no barrier ----
    {
    }
    const int rA = row0 + lx;                            // A-row this lane feeds
    const int bA = rA / 900;
    const int qA = rA - bA * 900;
    const float* hrow = hs + (((size_t)l * 900 + qA) * 32 + bA) * 256 + quad * 8;
    bf16x8 aH[8];
#pragma unroll
    for (int kk = 0; kk < 8; kk++) {
        float4 f0 = *(const float4*)(hrow + kk * 32);
        float4 f1 = *(const float4*)(hrow + kk * 32 + 4);
        aH[kk] = cvt8(f0, f1);
    }

    f32x4 acc[16];

    // ===== cls1: x1 = relu(LN(h@cw1+cb1)) -> slab =====
    gemmFR(aH, cw1t + (size_t)l * 65536, lane, acc);
    ln_epi(acc, cb1 + l * 256, g1 + l * 256, b1 + l * 256, lane);
    store_slab(slab, lane, acc);

    // ===== cls2: x2 = relu(LN(x1@cw2+cb2)) -> slab (in place; wave-ordered) =====
    gemmFR_lds(slab, cw2t + (size_t)l * 65536, lane, acc);
    ln_epi(acc, cb2 + l * 256, g2 + l * 256, b2 + l * 256, lane);
    store_slab(slab, lane, acc);

    // ===== cls3: out_cls = x2@cw3+cb3 =====
    {
        f32x4 c = gemm16(slab, cw3t + (size_t)l * 4096, lane);
        if (lx < 10) {
            const float bv = cb3[l * 10 + lx];
#pragma unroll
            for (int r = 0; r < 4; r++) {
                int row = row0 + quad * 4 + r;
                out[((size_t)l * 28800 + row) * 10 + lx] = c[r] + bv;
            }
        }
    }

    // ===== reg1: y1 = relu(h@rw1+rb1) -> slab (aH still in registers) =====
    gemmFR(aH, rw1t + (size_t)l * 65536, lane, acc);
    bias_epi(acc, rb1 + l * 256, lane);
    store_slab(slab, lane, acc);

    // ===== reg2: y2 = relu(y1@rw2+rb2) -> slab (in place) =====
    gemmFR_lds(slab, rw2t + (size_t)l * 65536, lane, acc);
    bias_epi(acc, rb2 + l * 256, lane);
    store_slab(slab, lane, acc);

    // ===== reg3: tmp = y2@rw3+rb3 -> coord transform -> out =====
    {
        f32x4 t = gemm16(slab, rw3t + (size_t)l * 4096, lane);
        if (lx < 10) {
            const float bv = rb3[l * 10 + lx];
            const float* refp = (l == 0) ? init_ref : (inter_ref + (size_t)(l - 1) * 28800 * 3);
#pragma unroll
            for (int r = 0; r < 4; r++) {
                int row = row0 + quad * 4 + r;
                float vv = t[r] + bv;
                float o;
                if (lx == 0 || lx == 1 || lx == 4) {
                    int rc = (lx == 4) ? 2 : lx;
                    float x = refp[(size_t)row * 3 + rc];
                    x = fminf(fmaxf(x, 0.f), 1.f);
                    float x1 = fmaxf(x, 1e-5f);
                    float x2 = fmaxf(1.f - x, 1e-5f);
                    float ris = logf(x1) - logf(x2);
                    float sg = 1.f / (1.f + expf(-(vv + ris)));
                    o = (lx == 4) ? (sg * 8.f - 5.f) : (sg * 102.4f - 51.2f);
                } else {
                    o = vv;
                }
                out[(size_t)(6 + l) * 28800 * 10 + (size_t)row * 10 + lx] = o;
            }
        }
    }
}

extern "C" void kernel_launch(void* const* d_in, const int* in_sizes, int n_in,
                              void* d_out, int out_size, void* d_ws, size_t ws_size,
                              hipStream_t stream)
{
    const float* hs        = (const float*)d_in[0];
    const float* init_ref  = (const float*)d_in[1];
    const float* inter_ref = (const float*)d_in[2];
    const float* cls_w1    = (const float*)d_in[3];
    const float* cls_b1    = (const float*)d_in[4];
    const float* ln1_g     = (const float*)d_in[5];
    const float* ln1_b     = (const float*)d_in[6];
    const float* cls_w2    = (const float*)d_in[7];
    const float* cls_b2    = (const float*)d_in[8];
    const float* ln2_g     = (const float*)d_in[9];
    const float* ln2_b     = (const float*)d_in[10];
    const float* cls_w3    = (const float*)d_in[11];
    const float* cls_b3    = (const float*)d_in[12];
    const float* reg_w1    = (const float*)d_in[13];
    const float* reg_b1    = (const float*)d_in[14];
    const float* reg_w2    = (const float*)d_in[15];
    const float* reg_b2    = (const float*)d_in[16];
    const float* reg_w3    = (const float*)d_in[17];
    const float* reg_b3    = (const float*)d_in[18];

    bf16* ws   = (bf16*)d_ws;
    bf16* cw1t = ws;                  // 4 contiguous 6*65536 regions (K-outer packed)
    bf16* cw2t = cw1t + 393216;
    bf16* rw1t = cw2t + 393216;
    bf16* rw2t = rw1t + 393216;
    bf16* cw3t = rw2t + 393216;       // 6*16*256
    bf16* rw3t = cw3t + 24576;

    transpose_all<<<dim3(4, 4, 24), 256, 0, stream>>>(cls_w1, cls_w2, reg_w1, reg_w2, cw1t);
    prep_small<<<192, 256, 0, stream>>>(cls_w3, reg_w3, cw3t, rw3t);

    head_kernel<<<dim3(450, 6), 256, 0, stream>>>(
        hs, init_ref, inter_ref,
        cw1t, cw2t, rw1t, rw2t, cw3t, rw3t,
        cls_b1, ln1_g, ln1_b, cls_b2, ln2_g, ln2_b, cls_b3,
        reg_b1, reg_b2, reg_b3, (float*)d_out);
}